// Round 5
// baseline (302.021 us; speedup 1.0000x reference)
//
#include <hip/hip_runtime.h>

#define VOCAB 50000
#define BROWS 4096
#define F 64
#define NCOLS 80            // 64 features + w_hi + w_lo + 14 zero pad
#define NT 5                // n-tiles of 16
#define SPLITS 16
#define NR 98               // K-tiles (of 32) per split
#define KT_TOTAL (SPLITS * NR)            // 1568
#define KPAD (KT_TOTAL * 32)              // 50176

typedef __attribute__((ext_vector_type(4))) float f32x4;
typedef __attribute__((ext_vector_type(8))) short s16x8;

__device__ __forceinline__ unsigned short f2bf(float f) {
    unsigned u = __builtin_bit_cast(unsigned, f);
    unsigned r = (u + 0x7FFFu + ((u >> 16) & 1u)) >> 16;   // round-to-nearest-even
    return (unsigned short)r;
}
__device__ __forceinline__ float bf2f(unsigned short b) {
    unsigned u = ((unsigned)b) << 16;
    return __builtin_bit_cast(float, u);
}

// --- kernel 1: w[k] = bias[k] - 0.5*||V[k]||^2 (0 for padded k) ---
__global__ void fm_prep_w(const float* __restrict__ V, const float* __restrict__ bias,
                          float* __restrict__ w) {
    int k = blockIdx.x * blockDim.x + threadIdx.x;
    if (k >= KPAD) return;
    float val = 0.f;
    if (k < VOCAB) {
        const float4* row = reinterpret_cast<const float4*>(V + (size_t)k * F);
        float ss = 0.f;
#pragma unroll
        for (int j = 0; j < F / 4; ++j) {
            float4 v = row[j];
            ss += v.x * v.x + v.y * v.y + v.z * v.z + v.w * v.w;
        }
        val = bias[k] - 0.5f * ss;
    }
    w[k] = val;
}

// --- kernel 2: pack B operand into MFMA 16x16x32 bf16 fragment order ---
// bfrag[(kt*NT + nt)*64 + lane] = uint4 of 8 bf16:
//   elem j = B[kt*32 + (lane>>4)*8 + j][nt*16 + (lane&15)]
// where B[k][n] = V[k][n] (n<64), w_hi[k] (n==64), w_lo[k] (n==65), 0 otherwise.
__global__ void fm_prep_bfrag(const float* __restrict__ V, const float* __restrict__ w,
                              uint4* __restrict__ bfrag) {
    int t = blockIdx.x * blockDim.x + threadIdx.x;
    if (t >= KT_TOTAL * NT * 64) return;
    int lane = t & 63;
    int tile = t >> 6;
    int nt = tile % NT;
    int kt = tile / NT;
    int n = nt * 16 + (lane & 15);
    int kbase = kt * 32 + (lane >> 4) * 8;
    unsigned short o[8];
#pragma unroll
    for (int j = 0; j < 8; ++j) {
        int k = kbase + j;
        float v = 0.f;
        if (k < VOCAB) {
            if (n < F) {
                v = V[(size_t)k * F + n];
            } else if (n == F) {
                v = w[k];                       // f2bf below -> w_hi
            } else if (n == F + 1) {
                float wv = w[k];
                v = wv - bf2f(f2bf(wv));        // residual -> w_lo
            }
        }
        o[j] = f2bf(v);
    }
    uint4 pk;
    pk.x = (unsigned)o[0] | ((unsigned)o[1] << 16);
    pk.y = (unsigned)o[2] | ((unsigned)o[3] << 16);
    pk.z = (unsigned)o[4] | ((unsigned)o[5] << 16);
    pk.w = (unsigned)o[6] | ((unsigned)o[7] << 16);
    bfrag[t] = pk;
}

// --- kernel 3: barrier-free split-K MFMA GEMM ---
// No LDS, no __syncthreads: each wave self-paced. B fragments loaded directly
// from L1/L2-resident bfrag into registers (double-buffered, 1-round ahead);
// x prefetched 2 rounds ahead. Compiler emits precise per-register waitcnts.
__global__ __launch_bounds__(256, 4) void fm_main(const int* __restrict__ x,
                                                  const uint4* __restrict__ bfrag,
                                                  float* __restrict__ part) {
    const int bid = blockIdx.x;
    // XCD-locality remap: XCD k (bid&7) sees only splits {2k, 2k+1} ->
    // bfrag working set per XCD-L2 ~= 1MB (fits 4MB).
    const int split = (bid & 7) * 2 + ((bid >> 3) & 1);
    const int mblock = bid >> 4;
    const int wave = threadIdx.x >> 6;
    const int lane = threadIdx.x & 63;
    const int kb = lane >> 4;                 // 0..3
    const int rowA = mblock * 64 + wave * 16 + (lane & 15);
    const int* __restrict__ xrow = x + (size_t)rowA * VOCAB;
    const int kt0 = split * NR;
    const uint4* __restrict__ bl = bfrag + lane;   // per-lane fragment base

    auto loadB = [&](int t, uint4* B) {       // 5 coalesced dwordx4, L1/L2-hit
        const uint4* p = bl + (size_t)(kt0 + t) * (NT * 64);
#pragma unroll
        for (int nt = 0; nt < NT; ++nt) B[nt] = p[nt * 64];
    };
    auto loadx = [&](int r, int4& a, int4& b) {
        const int k = (kt0 + r) * 32 + kb * 8;
        a = *reinterpret_cast<const int4*>(xrow + k);
        b = *reinterpret_cast<const int4*>(xrow + k + 4);
    };
    auto loadx_g = [&](int r, int4& a, int4& b) {
        const int k = (kt0 + r) * 32 + kb * 8;
        int v[8];
#pragma unroll
        for (int j = 0; j < 8; ++j) v[j] = (k + j < VOCAB) ? xrow[k + j] : 0;
        a = make_int4(v[0], v[1], v[2], v[3]);
        b = make_int4(v[4], v[5], v[6], v[7]);
    };
    auto prefx = [&](int r, int4& a, int4& b) {   // wave-uniform guard select
        if ((kt0 + r) * 32 + 31 < VOCAB) loadx(r, a, b);
        else                             loadx_g(r, a, b);
    };
    auto mk = [&](int4 a0, int4 a1) -> s16x8 {    // x in {0,1}: bf16(1.0)=0x3F80
        uint4 apk;
        apk.x = ((unsigned)a0.x + ((unsigned)a0.y << 16)) * 16256u;
        apk.y = ((unsigned)a0.z + ((unsigned)a0.w << 16)) * 16256u;
        apk.z = ((unsigned)a1.x + ((unsigned)a1.y << 16)) * 16256u;
        apk.w = ((unsigned)a1.z + ((unsigned)a1.w << 16)) * 16256u;
        return __builtin_bit_cast(s16x8, apk);
    };

    f32x4 acc[NT];
#pragma unroll
    for (int nt = 0; nt < NT; ++nt) acc[nt] = (f32x4){0.f, 0.f, 0.f, 0.f};

    uint4 B0[NT], B1[NT];
    int4 xa0, xb0, xa1, xb1;
    loadB(0, B0); loadx(0, xa0, xb0);
    loadB(1, B1); loadx(1, xa1, xb1);

    for (int r = 0; r < NR; r += 2) {
        {   // round r: consume B0 / x0, then refill slot 0 for round r+2
            s16x8 af = mk(xa0, xb0);
#pragma unroll
            for (int nt = 0; nt < NT; ++nt) {
                s16x8 bf = __builtin_bit_cast(s16x8, B0[nt]);
                acc[nt] = __builtin_amdgcn_mfma_f32_16x16x32_bf16(af, bf, acc[nt], 0, 0, 0);
            }
            if (r + 2 < NR) { loadB(r + 2, B0); prefx(r + 2, xa0, xb0); }
        }
        {   // round r+1: consume B1 / x1, refill slot 1 for round r+3
            s16x8 af = mk(xa1, xb1);
#pragma unroll
            for (int nt = 0; nt < NT; ++nt) {
                s16x8 bf = __builtin_bit_cast(s16x8, B1[nt]);
                acc[nt] = __builtin_amdgcn_mfma_f32_16x16x32_bf16(af, bf, acc[nt], 0, 0, 0);
            }
            if (r + 3 < NR) { loadB(r + 3, B1); prefx(r + 3, xa1, xb1); }
        }
    }

    // D layout: row = (lane>>4)*4 + r, col = lane&15 (within the 16x16 tile)
    float* __restrict__ p = part + (size_t)split * BROWS * NCOLS;
    int m0 = mblock * 64 + wave * 16 + kb * 4;
    int c0 = lane & 15;
#pragma unroll
    for (int nt = 0; nt < NT; ++nt)
#pragma unroll
        for (int r = 0; r < 4; ++r)
            p[(size_t)(m0 + r) * NCOLS + nt * 16 + c0] = acc[nt][r];
}

// --- kernel 4: reduce splits, square-sum, add linear term ---
__global__ void fm_reduce(const float* __restrict__ part, const float* __restrict__ gbias,
                          float* __restrict__ out) {
    int b = blockIdx.x * 4 + (threadIdx.x >> 6);
    int lane = threadIdx.x & 63;
    float acc = 0.f;
#pragma unroll
    for (int s = 0; s < SPLITS; ++s)
        acc += part[((size_t)s * BROWS + b) * NCOLS + lane];
    float sq = acc * acc;
    float ex = 0.f;
    if (lane < 16)       ex = part[((size_t)lane * BROWS + b) * NCOLS + F];
    else if (lane < 32)  ex = part[((size_t)(lane - 16) * BROWS + b) * NCOLS + F + 1];
#pragma unroll
    for (int off = 32; off; off >>= 1) {
        sq += __shfl_xor(sq, off, 64);
        ex += __shfl_xor(ex, off, 64);
    }
    if (lane == 0) out[b] = gbias[0] + ex + 0.5f * sq;
}

extern "C" void kernel_launch(void* const* d_in, const int* in_sizes, int n_in,
                              void* d_out, int out_size, void* d_ws, size_t ws_size,
                              hipStream_t stream) {
    const int*   x     = (const int*)d_in[0];
    const float* V     = (const float*)d_in[1];
    const float* bias  = (const float*)d_in[2];
    const float* gbias = (const float*)d_in[3];
    float* out = (float*)d_out;

    // workspace layout
    char* ws = (char*)d_ws;
    uint4* bfrag = (uint4*)ws;                                  // 8,028,160 B
    float* w     = (float*)(ws + (size_t)KT_TOTAL * NT * 64 * 16);
    float* part  = (float*)(ws + (size_t)KT_TOTAL * NT * 64 * 16 + (size_t)KPAD * 4);
    // total: 8,028,160 + 200,704 + 20,971,520 = 29,200,384 B

    fm_prep_w<<<(KPAD + 255) / 256, 256, 0, stream>>>(V, bias, w);
    fm_prep_bfrag<<<(KT_TOTAL * NT * 64 + 255) / 256, 256, 0, stream>>>(V, w, bfrag);
    fm_main<<<(BROWS / 64) * SPLITS, 256, 0, stream>>>(x, bfrag, part);
    fm_reduce<<<BROWS / 4, 256, 0, stream>>>(part, gbias, out);
}

// Round 6
// 208.094 us; speedup vs baseline: 1.4514x; 1.4514x over previous
//
#include <hip/hip_runtime.h>

#define VOCAB 50000
#define BROWS 4096
#define F 64
#define NCOLS 80            // 64 features + w_hi + w_lo + 14 zero pad
#define NT 5                // n-tiles of 16
#define SPLITS 16
#define NR 98               // K-tiles (of 32) per split
#define KT_TOTAL (SPLITS * NR)            // 1568
#define KPAD (KT_TOTAL * 32)              // 50176

#define AS1 __attribute__((address_space(1)))
#define AS3 __attribute__((address_space(3)))

typedef __attribute__((ext_vector_type(4))) float f32x4;
typedef __attribute__((ext_vector_type(8))) short s16x8;

__device__ __forceinline__ unsigned short f2bf(float f) {
    unsigned u = __builtin_bit_cast(unsigned, f);
    unsigned r = (u + 0x7FFFu + ((u >> 16) & 1u)) >> 16;   // round-to-nearest-even
    return (unsigned short)r;
}
__device__ __forceinline__ float bf2f(unsigned short b) {
    unsigned u = ((unsigned)b) << 16;
    return __builtin_bit_cast(float, u);
}

// --- kernel 1: w[k] = bias[k] - 0.5*||V[k]||^2 (0 for padded k) ---
__global__ void fm_prep_w(const float* __restrict__ V, const float* __restrict__ bias,
                          float* __restrict__ w) {
    int k = blockIdx.x * blockDim.x + threadIdx.x;
    if (k >= KPAD) return;
    float val = 0.f;
    if (k < VOCAB) {
        const float4* row = reinterpret_cast<const float4*>(V + (size_t)k * F);
        float ss = 0.f;
#pragma unroll
        for (int j = 0; j < F / 4; ++j) {
            float4 v = row[j];
            ss += v.x * v.x + v.y * v.y + v.z * v.z + v.w * v.w;
        }
        val = bias[k] - 0.5f * ss;
    }
    w[k] = val;
}

// --- kernel 2: pack B operand into MFMA 16x16x32 bf16 fragment order ---
// bfrag[(kt*NT + nt)*64 + lane] = uint4 of 8 bf16:
//   elem j = B[kt*32 + (lane>>4)*8 + j][nt*16 + (lane&15)]
// where B[k][n] = V[k][n] (n<64), w_hi[k] (n==64), w_lo[k] (n==65), 0 otherwise.
__global__ void fm_prep_bfrag(const float* __restrict__ V, const float* __restrict__ w,
                              uint4* __restrict__ bfrag) {
    int t = blockIdx.x * blockDim.x + threadIdx.x;
    if (t >= KT_TOTAL * NT * 64) return;
    int lane = t & 63;
    int tile = t >> 6;
    int nt = tile % NT;
    int kt = tile / NT;
    int n = nt * 16 + (lane & 15);
    int kbase = kt * 32 + (lane >> 4) * 8;
    unsigned short o[8];
#pragma unroll
    for (int j = 0; j < 8; ++j) {
        int k = kbase + j;
        float v = 0.f;
        if (k < VOCAB) {
            if (n < F) {
                v = V[(size_t)k * F + n];
            } else if (n == F) {
                v = w[k];                       // f2bf below -> w_hi
            } else if (n == F + 1) {
                float wv = w[k];
                v = wv - bf2f(f2bf(wv));        // residual -> w_lo
            }
        }
        o[j] = f2bf(v);
    }
    uint4 pk;
    pk.x = (unsigned)o[0] | ((unsigned)o[1] << 16);
    pk.y = (unsigned)o[2] | ((unsigned)o[3] << 16);
    pk.z = (unsigned)o[4] | ((unsigned)o[5] << 16);
    pk.w = (unsigned)o[6] | ((unsigned)o[7] << 16);
    bfrag[t] = pk;
}

// --- kernel 3: R2 structure (LDS dbuf B + per-round syncthreads) with
//     x loads BATCHED 4 rounds deep: each row's requests issue as one
//     512B-contiguous clump -> 4x fewer DRAM page activations. ---
__global__ __launch_bounds__(256, 4) void fm_main(const int* __restrict__ x,
                                                  const uint4* __restrict__ bfrag,
                                                  float* __restrict__ part) {
    __shared__ uint4 bbuf[2][NT * 64];        // 2 x 5120 B
    const int bx = blockIdx.x;
    const int split = bx & (SPLITS - 1);      // XCD bx&7 already sees only 2 splits
    const int mblock = bx >> 4;
    const int tid = threadIdx.x;
    const int wave = tid >> 6;
    const int lane = tid & 63;
    const int kb = lane >> 4;                 // 0..3
    const int rowA = mblock * 64 + wave * 16 + (lane & 15);
    const int* __restrict__ xrow = x + (size_t)rowA * VOCAB;
    const int kt0 = split * NR;
    const int e0 = (wave << 6) + lane;

    auto stage = [&](int rnd) {               // 320 uint4 (one B-tile) -> bbuf[rnd&1]
        const uint4* src = bfrag + (size_t)(kt0 + rnd) * (NT * 64);
        uint4* dst = bbuf[rnd & 1];
        __builtin_amdgcn_global_load_lds((const AS1 void*)(src + e0),
                                         (AS3 void*)(dst + (wave << 6)), 16, 0, 0);
        if (wave == 0)                        // elems 256..319
            __builtin_amdgcn_global_load_lds((const AS1 void*)(src + 256 + lane),
                                             (AS3 void*)(dst + 256), 16, 0, 0);
    };
    // batch-load x for rounds r0..r0+3 into d[0..7] (8 dwordx4 back-to-back;
    // the lane-group's requests cover 512B contiguous per row)
    auto batchload = [&](int r0, int4* d) {
#pragma unroll
        for (int j = 0; j < 4; ++j) {
            const int r = r0 + j;
            if (r >= NR) continue;            // wave-uniform
            const int k = (kt0 + r) * 32 + kb * 8;
            if ((kt0 + r) * 32 + 32 <= VOCAB) {           // wave-uniform
                d[2 * j]     = *reinterpret_cast<const int4*>(xrow + k);
                d[2 * j + 1] = *reinterpret_cast<const int4*>(xrow + k + 4);
            } else {                           // guarded (split 15, kt>=1562)
                int v[8];
#pragma unroll
                for (int jj = 0; jj < 8; ++jj) v[jj] = (k + jj < VOCAB) ? xrow[k + jj] : 0;
                d[2 * j]     = make_int4(v[0], v[1], v[2], v[3]);
                d[2 * j + 1] = make_int4(v[4], v[5], v[6], v[7]);
            }
        }
    };
    auto mk = [&](int4 a0, int4 a1) -> s16x8 { // x in {0,1}: bf16(1.0) = 0x3F80
        uint4 apk;
        apk.x = ((unsigned)a0.x + ((unsigned)a0.y << 16)) * 16256u;
        apk.y = ((unsigned)a0.z + ((unsigned)a0.w << 16)) * 16256u;
        apk.z = ((unsigned)a1.x + ((unsigned)a1.y << 16)) * 16256u;
        apk.w = ((unsigned)a1.z + ((unsigned)a1.w << 16)) * 16256u;
        return __builtin_bit_cast(s16x8, apk);
    };

    f32x4 acc[NT];
#pragma unroll
    for (int nt = 0; nt < NT; ++nt) acc[nt] = (f32x4){0.f, 0.f, 0.f, 0.f};

    auto roundbody = [&](int r, int4 a0, int4 a1) {
        if (r + 1 < NR) stage(r + 1);         // B for next round -> other buffer
        s16x8 af = mk(a0, a1);
        const uint4* bb = bbuf[r & 1];
#pragma unroll
        for (int nt = 0; nt < NT; ++nt) {
            s16x8 bf = __builtin_bit_cast(s16x8, bb[nt * 64 + lane]);
            acc[nt] = __builtin_amdgcn_mfma_f32_16x16x32_bf16(af, bf, acc[nt], 0, 0, 0);
        }
        __syncthreads();
    };

    int4 xcur[8], xnxt[8];
    stage(0);
    batchload(0, xcur);                       // rounds 0..3
    __syncthreads();

    for (int s = 0; s < 12; ++s) {            // 8 rounds per iter: 0..95
        const int r0 = 8 * s;
        // phase A: refill xnxt (rounds r0+4..r0+7), consume xcur (r0..r0+3)
        batchload(r0 + 4, xnxt);
        roundbody(r0 + 0, xcur[0], xcur[1]);
        roundbody(r0 + 1, xcur[2], xcur[3]);
        roundbody(r0 + 2, xcur[4], xcur[5]);
        roundbody(r0 + 3, xcur[6], xcur[7]);
        // phase B: refill xcur (rounds r0+8..r0+11), consume xnxt
        batchload(r0 + 8, xcur);
        roundbody(r0 + 4, xnxt[0], xnxt[1]);
        roundbody(r0 + 5, xnxt[2], xnxt[3]);
        roundbody(r0 + 6, xnxt[4], xnxt[5]);
        roundbody(r0 + 7, xnxt[6], xnxt[7]);
    }
    // tail rounds 96, 97 (xcur loaded at s=11 phase B; rounds 98/99 skipped)
    roundbody(96, xcur[0], xcur[1]);
    roundbody(97, xcur[2], xcur[3]);

    // D layout: row = (lane>>4)*4 + r, col = lane&15 (within the 16x16 tile)
    float* __restrict__ p = part + (size_t)split * BROWS * NCOLS;
    int m0 = mblock * 64 + wave * 16 + kb * 4;
    int c0 = lane & 15;
#pragma unroll
    for (int nt = 0; nt < NT; ++nt)
#pragma unroll
        for (int r = 0; r < 4; ++r)
            p[(size_t)(m0 + r) * NCOLS + nt * 16 + c0] = acc[nt][r];
}

// --- kernel 4: reduce splits, square-sum, add linear term ---
__global__ void fm_reduce(const float* __restrict__ part, const float* __restrict__ gbias,
                          float* __restrict__ out) {
    int b = blockIdx.x * 4 + (threadIdx.x >> 6);
    int lane = threadIdx.x & 63;
    float acc = 0.f;
#pragma unroll
    for (int s = 0; s < SPLITS; ++s)
        acc += part[((size_t)s * BROWS + b) * NCOLS + lane];
    float sq = acc * acc;
    float ex = 0.f;
    if (lane < 16)       ex = part[((size_t)lane * BROWS + b) * NCOLS + F];
    else if (lane < 32)  ex = part[((size_t)(lane - 16) * BROWS + b) * NCOLS + F + 1];
#pragma unroll
    for (int off = 32; off; off >>= 1) {
        sq += __shfl_xor(sq, off, 64);
        ex += __shfl_xor(ex, off, 64);
    }
    if (lane == 0) out[b] = gbias[0] + ex + 0.5f * sq;
}

extern "C" void kernel_launch(void* const* d_in, const int* in_sizes, int n_in,
                              void* d_out, int out_size, void* d_ws, size_t ws_size,
                              hipStream_t stream) {
    const int*   x     = (const int*)d_in[0];
    const float* V     = (const float*)d_in[1];
    const float* bias  = (const float*)d_in[2];
    const float* gbias = (const float*)d_in[3];
    float* out = (float*)d_out;

    // workspace layout
    char* ws = (char*)d_ws;
    uint4* bfrag = (uint4*)ws;                                  // 8,028,160 B
    float* w     = (float*)(ws + (size_t)KT_TOTAL * NT * 64 * 16);
    float* part  = (float*)(ws + (size_t)KT_TOTAL * NT * 64 * 16 + (size_t)KPAD * 4);
    // total: 8,028,160 + 200,704 + 20,971,520 = 29,200,384 B

    fm_prep_w<<<(KPAD + 255) / 256, 256, 0, stream>>>(V, bias, w);
    fm_prep_bfrag<<<(KT_TOTAL * NT * 64 + 255) / 256, 256, 0, stream>>>(V, w, bfrag);
    fm_main<<<(BROWS / 64) * SPLITS, 256, 0, stream>>>(x, bfrag, part);
    fm_reduce<<<BROWS / 4, 256, 0, stream>>>(part, gbias, out);
}